// Round 10
// baseline (1947.887 us; speedup 1.0000x reference)
//
#include <hip/hip_runtime.h>
#include <stdint.h>

#define NN   50000
#define NE   1600000
#define DIN  128
#define DMID 256
#define DOUT 128
#define NMID 8

#define AS1 __attribute__((address_space(1)))
#define AS3 __attribute__((address_space(3)))

typedef unsigned short u16;
typedef unsigned int   u32;
typedef __attribute__((ext_vector_type(8))) short short8;
typedef __attribute__((ext_vector_type(4))) float f32x4;
typedef __attribute__((ext_vector_type(2))) float f32x2;
typedef __attribute__((ext_vector_type(4))) int i32x4;

__device__ __forceinline__ float bf2f(u32 u) {
    union { u32 i; float f; } c; c.i = u << 16; return c.f;
}
__device__ __forceinline__ u16 f2bf(float f) {
    union { float f; u32 i; } c; c.f = f;
    u32 u = c.i;
    return (u16)((u + 0x7fffu + ((u >> 16) & 1u)) >> 16);
}
__device__ __forceinline__ void split2(float v, u16& hi, u16& lo) {
    hi = f2bf(v);
    float r = v - bf2f(hi);
    lo = f2bf(r);
}

// ---------------- preprocessing ----------------
// pass 1: per-edge rank within its dst bucket; counts[] is the histogram after.
__global__ void rank_kernel(const int* __restrict__ ei, int* __restrict__ counts,
                            int* __restrict__ rank) {
    int i = (blockIdx.x * blockDim.x + threadIdx.x) * 4;
    if (i < NE) {
        i32x4 d = *(const i32x4*)(ei + NE + i);
        i32x4 r;
        r.x = atomicAdd(&counts[d.x], 1);
        r.y = atomicAdd(&counts[d.y], 1);
        r.z = atomicAdd(&counts[d.z], 1);
        r.w = atomicAdd(&counts[d.w], 1);
        *(i32x4*)(rank + i) = r;
    }
}

__global__ void dinv_kernel(const int* __restrict__ counts, float* __restrict__ dinv) {
    int i = blockIdx.x * blockDim.x + threadIdx.x;
    if (i < NN) dinv[i] = rsqrtf((float)counts[i] + 1.0f);
}

__global__ __launch_bounds__(1024) void scan_kernel(const int* __restrict__ counts,
                                                    int* __restrict__ rowp) {
    __shared__ int sh[1024];
    const int t = threadIdx.x;
    constexpr int ITEMS = (NN + 1023) / 1024;  // 49
    const int start = t * ITEMS;
    int sum = 0;
    for (int j = 0; j < ITEMS; ++j) {
        int idx = start + j;
        if (idx < NN) sum += counts[idx];
    }
    sh[t] = sum;
    __syncthreads();
    for (int offs = 1; offs < 1024; offs <<= 1) {
        int v = (t >= offs) ? sh[t - offs] : 0;
        __syncthreads();
        sh[t] += v;
        __syncthreads();
    }
    int base = (t == 0) ? 0 : sh[t - 1];
    for (int j = 0; j < ITEMS; ++j) {
        int idx = start + j;
        if (idx < NN) {
            rowp[idx] = base;
            base += counts[idx];
        }
    }
    if (t == 0) rowp[NN] = NE;
}

// pass 2: scatter src ids into CSR slots (no atomics).
__global__ void scatter_kernel(const int* __restrict__ ei, const int* __restrict__ rowp,
                               const int* __restrict__ rank, int* __restrict__ srcs) {
    int i = (blockIdx.x * blockDim.x + threadIdx.x) * 4;
    if (i < NE) {
        i32x4 d = *(const i32x4*)(ei + NE + i);
        i32x4 s = *(const i32x4*)(ei + i);
        i32x4 r = *(const i32x4*)(rank + i);
        srcs[rowp[d.x] + r.x] = s.x;
        srcs[rowp[d.y] + r.y] = s.y;
        srcs[rowp[d.z] + r.z] = s.z;
        srcs[rowp[d.w] + r.w] = s.w;
    }
}

// W [K x Dc] fp32 row-major -> slice-major bf16 split: Whi[((k/32)*Dc + d)*32 + k%32]
__global__ void wsplit_kernel(const float* __restrict__ W, u16* __restrict__ Whi,
                              u16* __restrict__ Wlo, int K, int Dc) {
    int idx = blockIdx.x * blockDim.x + threadIdx.x;
    if (idx < K * Dc) {
        int k = idx / Dc, d = idx - k * Dc;
        u16 hi, lo;
        split2(W[idx], hi, lo);
        size_t o = ((size_t)(k >> 5) * Dc + d) * 32 + (k & 31);
        Whi[o] = hi;
        Wlo[o] = lo;
    }
}

// x [NN][128] fp32 -> row-major bf16 hi/lo
__global__ void xsplit_kernel(const float* __restrict__ x, u16* __restrict__ xhi,
                              u16* __restrict__ xlo) {
    int i = blockIdx.x * blockDim.x + threadIdx.x;
    int stride = gridDim.x * blockDim.x;
    for (; i < NN * DIN; i += stride) {
        u16 hi, lo;
        split2(x[i], hi, lo);
        xhi[i] = hi;
        xlo[i] = lo;
    }
}

// ---------------- GEMM v4: g = (x @ W) * dinv[row], bf16 row-major out -------
// 512 threads = 8 waves as 2 row-panels x 4 col-panels over a 128 x Dc tile.
// Wave: 64 rows (4 rg of 16) x Dc/4 cols (NTW tiles of 16). Per K-slice per
// wave: 8 ds_read_b128, 48 MFMA (6:1 — v3's win); per block per slice: 384
// MFMA per 64KB staged (v2's win). 3-pass split-bf16 MFMA.
// C/D: col=lane&15, row=quad*4+reg.

template <int K, int Dc>
__global__ __launch_bounds__(512) void gemm_kernel(const u16* __restrict__ xhi,
                                                   const u16* __restrict__ xlo,
                                                   const u16* __restrict__ whi,
                                                   const u16* __restrict__ wlo,
                                                   const float* __restrict__ dinv,
                                                   u16* __restrict__ g) {
    constexpr int NTW = Dc / 64;   // col-tiles per wave (4 for 256, 2 for 128)
    constexpr int KS = K / 32;
    __shared__ u16 bh[Dc * 32];
    __shared__ u16 bl[Dc * 32];
    const int tid = threadIdx.x;
    const int wid = tid >> 6;
    const int rowPanel = wid >> 2;       // 0..1
    const int colPanel = wid & 3;        // 0..3
    const int lane = tid & 63;
    const int m = lane & 15, quad = lane >> 4;
    const int rowBase = blockIdx.x * 128 + rowPanel * 64;

    f32x4 acc[4][NTW];
#pragma unroll
    for (int rg = 0; rg < 4; ++rg)
#pragma unroll
        for (int t = 0; t < NTW; ++t) acc[rg][t] = (f32x4){0.f, 0.f, 0.f, 0.f};

    size_t arow[4];
#pragma unroll
    for (int rg = 0; rg < 4; ++rg) {
        int rowA = rowBase + rg * 16 + m;
        if (rowA > NN - 1) rowA = NN - 1;
        arow[rg] = (size_t)rowA * K + quad * 8;
    }

    for (int ks = 0; ks < KS; ++ks) {
        const u16* sh_src = whi + (size_t)ks * Dc * 32;
        const u16* sl_src = wlo + (size_t)ks * Dc * 32;
        __syncthreads();  // protect LDS from previous iteration's readers
#pragma unroll
        for (int i = 0; i < Dc * 4; i += 512) {
            int j = i + tid;
            __builtin_amdgcn_global_load_lds((const AS1 void*)(sh_src + j * 8),
                                             (AS3 void*)((AS3 u16*)bh + j * 8), 16, 0, 0);
            __builtin_amdgcn_global_load_lds((const AS1 void*)(sl_src + j * 8),
                                             (AS3 void*)((AS3 u16*)bl + j * 8), 16, 0, 0);
        }
        short8 ah[4], al[4];
#pragma unroll
        for (int rg = 0; rg < 4; ++rg) {
            ah[rg] = *(const short8*)(xhi + arow[rg] + ks * 32);
            al[rg] = *(const short8*)(xlo + arow[rg] + ks * 32);
        }
        __syncthreads();  // staging complete
#pragma unroll
        for (int t = 0; t < NTW; ++t) {
            const int bo = ((colPanel * NTW + t) * 16 + m) * 32 + quad * 8;
            short8 wh = *(const short8*)(bh + bo);
            short8 wl = *(const short8*)(bl + bo);
#pragma unroll
            for (int rg = 0; rg < 4; ++rg) {
                acc[rg][t] = __builtin_amdgcn_mfma_f32_16x16x32_bf16(ah[rg], wh, acc[rg][t], 0, 0, 0);
                acc[rg][t] = __builtin_amdgcn_mfma_f32_16x16x32_bf16(al[rg], wh, acc[rg][t], 0, 0, 0);
                acc[rg][t] = __builtin_amdgcn_mfma_f32_16x16x32_bf16(ah[rg], wl, acc[rg][t], 0, 0, 0);
            }
        }
    }

#pragma unroll
    for (int rg = 0; rg < 4; ++rg) {
        const int r0 = rowBase + rg * 16 + quad * 4;
        float dv[4];
#pragma unroll
        for (int r = 0; r < 4; ++r) {
            int rr = r0 + r;
            dv[r] = (rr < NN) ? dinv[rr] : 0.f;
        }
#pragma unroll
        for (int t = 0; t < NTW; ++t) {
            const int col = colPanel * (Dc / 4) + t * 16 + m;
#pragma unroll
            for (int r = 0; r < 4; ++r) {
                int rr = r0 + r;
                if (rr < NN) g[(size_t)rr * Dc + col] = f2bf(acc[rg][t][r] * dv[r]);
            }
        }
    }
}

// ---------------- full-row aggregation + fused bias/LN/SiLU/split ------------
// wave per node; lane owns L = Dc/64 consecutive bf16 columns (full 512B row per
// edge = 8 contiguous lines -> at load-return BW ceiling). 8-deep unrolled.

template <int L>
__device__ __forceinline__ void loadg(const u16* p, float (&f)[L]);
template <>
__device__ __forceinline__ void loadg<4>(const u16* p, float (&f)[4]) {
    uint2 v = *(const uint2*)p;
    f[0] = bf2f(v.x & 0xffffu); f[1] = bf2f(v.x >> 16);
    f[2] = bf2f(v.y & 0xffffu); f[3] = bf2f(v.y >> 16);
}
template <>
__device__ __forceinline__ void loadg<2>(const u16* p, float (&f)[2]) {
    u32 v = *(const u32*)p;
    f[0] = bf2f(v & 0xffffu); f[1] = bf2f(v >> 16);
}

template <int Dc, bool FINAL>
__global__ __launch_bounds__(256) void agg_kernel(const u16* __restrict__ g,
                                                  const int* __restrict__ rowp,
                                                  const int* __restrict__ srcs,
                                                  const float* __restrict__ dinv,
                                                  const float* __restrict__ bias,
                                                  const float* __restrict__ gamma,
                                                  const float* __restrict__ beta,
                                                  float* __restrict__ outf,
                                                  u16* __restrict__ xhi,
                                                  u16* __restrict__ xlo) {
    constexpr int L = Dc / 64;
    const int wid = threadIdx.x >> 6, lane = threadIdx.x & 63;
    const int node = blockIdx.x * 4 + wid;
    const int coff = lane * L;

    float acc[L];
    loadg<L>(g + (size_t)node * Dc + coff, acc);  // self term

    int e = rowp[node];
    const int end = rowp[node + 1];
    for (; e + 8 <= end; e += 8) {
        int s0 = srcs[e],     s1 = srcs[e + 1], s2 = srcs[e + 2], s3 = srcs[e + 3];
        int s4 = srcs[e + 4], s5 = srcs[e + 5], s6 = srcs[e + 6], s7 = srcs[e + 7];
        float f0[L], f1[L], f2[L], f3[L], f4[L], f5[L], f6[L], f7[L];
        loadg<L>(g + (size_t)s0 * Dc + coff, f0);
        loadg<L>(g + (size_t)s1 * Dc + coff, f1);
        loadg<L>(g + (size_t)s2 * Dc + coff, f2);
        loadg<L>(g + (size_t)s3 * Dc + coff, f3);
        loadg<L>(g + (size_t)s4 * Dc + coff, f4);
        loadg<L>(g + (size_t)s5 * Dc + coff, f5);
        loadg<L>(g + (size_t)s6 * Dc + coff, f6);
        loadg<L>(g + (size_t)s7 * Dc + coff, f7);
#pragma unroll
        for (int j = 0; j < L; ++j)
            acc[j] += ((f0[j] + f1[j]) + (f2[j] + f3[j])) +
                      ((f4[j] + f5[j]) + (f6[j] + f7[j]));
    }
    for (; e < end; ++e) {
        float f[L];
        loadg<L>(g + (size_t)srcs[e] * Dc + coff, f);
#pragma unroll
        for (int j = 0; j < L; ++j) acc[j] += f[j];
    }

    const float dv = dinv[node];
    float v[L];
#pragma unroll
    for (int j = 0; j < L; ++j) v[j] = acc[j] * dv + bias[coff + j];

    if (FINAL) {
        if (L == 4) {
            f32x4 o = {v[0], v[1], v[2], v[3]};
            *(f32x4*)(outf + (size_t)node * Dc + coff) = o;
        } else {
            f32x2 o = {v[0], v[1]};
            *(f32x2*)(outf + (size_t)node * Dc + coff) = o;
        }
    } else {
        float s = 0.f, s2 = 0.f;
#pragma unroll
        for (int j = 0; j < L; ++j) {
            s += v[j];
            s2 += v[j] * v[j];
        }
        for (int off = 32; off > 0; off >>= 1) {
            s += __shfl_xor(s, off, 64);
            s2 += __shfl_xor(s2, off, 64);
        }
        const float mu = s * (1.f / Dc);
        const float var = s2 * (1.f / Dc) - mu * mu;
        const float rstd = rsqrtf(fmaxf(var, 0.f) + 1e-5f);
#pragma unroll
        for (int j = 0; j < L; ++j) {
            float y = (v[j] - mu) * rstd * gamma[coff + j] + beta[coff + j];
            v[j] = y / (1.f + __expf(-y));
        }
        u16 hh[L], ll[L];
#pragma unroll
        for (int j = 0; j < L; ++j) split2(v[j], hh[j], ll[j]);
        if (L == 4) {
            uint2 oh, ol;
            oh.x = (u32)hh[0] | ((u32)hh[1] << 16);
            oh.y = (u32)hh[2] | ((u32)hh[3] << 16);
            ol.x = (u32)ll[0] | ((u32)ll[1] << 16);
            ol.y = (u32)ll[2] | ((u32)ll[3] << 16);
            *(uint2*)(xhi + (size_t)node * Dc + coff) = oh;
            *(uint2*)(xlo + (size_t)node * Dc + coff) = ol;
        } else {
            *(u32*)(xhi + (size_t)node * Dc + coff) = (u32)hh[0] | ((u32)hh[1] << 16);
            *(u32*)(xlo + (size_t)node * Dc + coff) = (u32)ll[0] | ((u32)ll[1] << 16);
        }
    }
}

// ---------------- launcher ----------------

extern "C" void kernel_launch(void* const* d_in, const int* in_sizes, int n_in,
                              void* d_out, int out_size, void* d_ws, size_t ws_size,
                              hipStream_t stream) {
    (void)in_sizes; (void)n_in; (void)out_size; (void)ws_size;
    const float* x_in  = (const float*)d_in[0];
    const int*   ei    = (const int*)d_in[1];
    const float* W_in  = (const float*)d_in[2];
    const float* b_in  = (const float*)d_in[3];
    const float* W_mid = (const float*)d_in[4];
    const float* b_mid = (const float*)d_in[5];
    const float* W_out = (const float*)d_in[6];
    const float* b_out = (const float*)d_in[7];
    const float* gamma = (const float*)d_in[8];
    const float* beta  = (const float*)d_in[9];

    char* ws = (char*)d_ws;
    size_t off = 0;
    auto alloc = [&](size_t bytes) -> char* {
        char* p = ws + off;
        off += (bytes + 255) & ~(size_t)255;
        return p;
    };
    float* dinv   = (float*)alloc((size_t)NN * 4);
    int* counts   = (int*)alloc((size_t)NN * 4);
    int* rowp     = (int*)alloc((size_t)(NN + 1) * 4);
    int* rank     = (int*)alloc((size_t)NE * 4);
    int* srcs     = (int*)alloc((size_t)NE * 4);
    u16* whi_in   = (u16*)alloc((size_t)DIN * DMID * 2);
    u16* wlo_in   = (u16*)alloc((size_t)DIN * DMID * 2);
    u16* whi_mid  = (u16*)alloc((size_t)NMID * DMID * DMID * 2);
    u16* wlo_mid  = (u16*)alloc((size_t)NMID * DMID * DMID * 2);
    u16* whi_out  = (u16*)alloc((size_t)DMID * DOUT * 2);
    u16* wlo_out  = (u16*)alloc((size_t)DMID * DOUT * 2);
    u16* xhi      = (u16*)alloc((size_t)NN * DMID * 2);
    u16* xlo      = (u16*)alloc((size_t)NN * DMID * 2);
    u16* g        = (u16*)alloc((size_t)NN * DMID * 2);

    hipMemsetAsync(counts, 0, (size_t)NN * 4, stream);
    const int EB4 = (NE / 4 + 255) / 256;  // 1563: one int4 group per thread
    rank_kernel<<<EB4, 256, 0, stream>>>(ei, counts, rank);
    dinv_kernel<<<(NN + 255) / 256, 256, 0, stream>>>(counts, dinv);
    scan_kernel<<<1, 1024, 0, stream>>>(counts, rowp);
    scatter_kernel<<<EB4, 256, 0, stream>>>(ei, rowp, rank, srcs);

    wsplit_kernel<<<(DIN * DMID + 255) / 256, 256, 0, stream>>>(W_in, whi_in, wlo_in, DIN, DMID);
    for (int i = 0; i < NMID; ++i)
        wsplit_kernel<<<(DMID * DMID + 255) / 256, 256, 0, stream>>>(
            W_mid + (size_t)i * DMID * DMID, whi_mid + (size_t)i * DMID * DMID,
            wlo_mid + (size_t)i * DMID * DMID, DMID, DMID);
    wsplit_kernel<<<(DMID * DOUT + 255) / 256, 256, 0, stream>>>(W_out, whi_out, wlo_out, DMID, DOUT);
    xsplit_kernel<<<1024, 256, 0, stream>>>(x_in, xhi, xlo);

    const int GB = (NN + 127) / 128;  // 391 (8 waves/block, 128x Dc tile)
    const int NB = NN / 4;            // 12500 (4 waves/block, wave per node)

    // layer 0: 128 -> 256
    gemm_kernel<DIN, DMID><<<GB, 512, 0, stream>>>(xhi, xlo, whi_in, wlo_in, dinv, g);
    agg_kernel<DMID, false><<<NB, 256, 0, stream>>>(g, rowp, srcs, dinv, b_in,
                                                    gamma, beta, nullptr, xhi, xlo);
    // 8 mid layers: 256 -> 256
    for (int i = 0; i < NMID; ++i) {
        gemm_kernel<DMID, DMID><<<GB, 512, 0, stream>>>(xhi, xlo,
                                                        whi_mid + (size_t)i * DMID * DMID,
                                                        wlo_mid + (size_t)i * DMID * DMID,
                                                        dinv, g);
        agg_kernel<DMID, false><<<NB, 256, 0, stream>>>(g, rowp, srcs, dinv,
                                                        b_mid + (size_t)i * DMID,
                                                        gamma + (size_t)(i + 1) * DMID,
                                                        beta + (size_t)(i + 1) * DMID,
                                                        nullptr, xhi, xlo);
    }
    // final layer: 256 -> 128, no LN/SiLU
    gemm_kernel<DMID, DOUT><<<GB, 512, 0, stream>>>(xhi, xlo, whi_out, wlo_out, dinv, g);
    agg_kernel<DOUT, true><<<NB, 256, 0, stream>>>(g, rowp, srcs, dinv, b_out,
                                                   nullptr, nullptr, (float*)d_out,
                                                   nullptr, nullptr);
}

// Round 11
// 1653.985 us; speedup vs baseline: 1.1777x; 1.1777x over previous
//
#include <hip/hip_runtime.h>
#include <stdint.h>

#define NN   50000
#define NE   1600000
#define DIN  128
#define DMID 256
#define DOUT 128
#define NMID 8

#define AS1 __attribute__((address_space(1)))
#define AS3 __attribute__((address_space(3)))

typedef unsigned short u16;
typedef unsigned int   u32;
typedef __attribute__((ext_vector_type(8))) short short8;
typedef __attribute__((ext_vector_type(4))) float f32x4;
typedef __attribute__((ext_vector_type(2))) float f32x2;
typedef __attribute__((ext_vector_type(4))) int i32x4;

__device__ __forceinline__ float bf2f(u32 u) {
    union { u32 i; float f; } c; c.i = u << 16; return c.f;
}
__device__ __forceinline__ u16 f2bf(float f) {
    union { float f; u32 i; } c; c.f = f;
    u32 u = c.i;
    return (u16)((u + 0x7fffu + ((u >> 16) & 1u)) >> 16);
}
__device__ __forceinline__ void split2(float v, u16& hi, u16& lo) {
    hi = f2bf(v);
    float r = v - bf2f(hi);
    lo = f2bf(r);
}

// ---------------- preprocessing ----------------
// pass 1: per-edge rank within its dst bucket; counts[] is the histogram after.
__global__ void rank_kernel(const int* __restrict__ ei, int* __restrict__ counts,
                            int* __restrict__ rank) {
    int i = (blockIdx.x * blockDim.x + threadIdx.x) * 4;
    if (i < NE) {
        i32x4 d = *(const i32x4*)(ei + NE + i);
        i32x4 r;
        r.x = atomicAdd(&counts[d.x], 1);
        r.y = atomicAdd(&counts[d.y], 1);
        r.z = atomicAdd(&counts[d.z], 1);
        r.w = atomicAdd(&counts[d.w], 1);
        *(i32x4*)(rank + i) = r;
    }
}

__global__ void dinv_kernel(const int* __restrict__ counts, float* __restrict__ dinv) {
    int i = blockIdx.x * blockDim.x + threadIdx.x;
    if (i < NN) dinv[i] = rsqrtf((float)counts[i] + 1.0f);
}

__global__ __launch_bounds__(1024) void scan_kernel(const int* __restrict__ counts,
                                                    int* __restrict__ rowp) {
    __shared__ int sh[1024];
    const int t = threadIdx.x;
    constexpr int ITEMS = (NN + 1023) / 1024;  // 49
    const int start = t * ITEMS;
    int sum = 0;
    for (int j = 0; j < ITEMS; ++j) {
        int idx = start + j;
        if (idx < NN) sum += counts[idx];
    }
    sh[t] = sum;
    __syncthreads();
    for (int offs = 1; offs < 1024; offs <<= 1) {
        int v = (t >= offs) ? sh[t - offs] : 0;
        __syncthreads();
        sh[t] += v;
        __syncthreads();
    }
    int base = (t == 0) ? 0 : sh[t - 1];
    for (int j = 0; j < ITEMS; ++j) {
        int idx = start + j;
        if (idx < NN) {
            rowp[idx] = base;
            base += counts[idx];
        }
    }
    if (t == 0) rowp[NN] = NE;
}

// pass 2: scatter src ids into CSR slots (no atomics).
__global__ void scatter_kernel(const int* __restrict__ ei, const int* __restrict__ rowp,
                               const int* __restrict__ rank, int* __restrict__ srcs) {
    int i = (blockIdx.x * blockDim.x + threadIdx.x) * 4;
    if (i < NE) {
        i32x4 d = *(const i32x4*)(ei + NE + i);
        i32x4 s = *(const i32x4*)(ei + i);
        i32x4 r = *(const i32x4*)(rank + i);
        srcs[rowp[d.x] + r.x] = s.x;
        srcs[rowp[d.y] + r.y] = s.y;
        srcs[rowp[d.z] + r.z] = s.z;
        srcs[rowp[d.w] + r.w] = s.w;
    }
}

// W [K x Dc] fp32 row-major -> slice-major bf16 split: Whi[((k/32)*Dc + d)*32 + k%32]
__global__ void wsplit_kernel(const float* __restrict__ W, u16* __restrict__ Whi,
                              u16* __restrict__ Wlo, int K, int Dc) {
    int idx = blockIdx.x * blockDim.x + threadIdx.x;
    if (idx < K * Dc) {
        int k = idx / Dc, d = idx - k * Dc;
        u16 hi, lo;
        split2(W[idx], hi, lo);
        size_t o = ((size_t)(k >> 5) * Dc + d) * 32 + (k & 31);
        Whi[o] = hi;
        Wlo[o] = lo;
    }
}

// x [NN][128] fp32 -> row-major bf16 hi/lo
__global__ void xsplit_kernel(const float* __restrict__ x, u16* __restrict__ xhi,
                              u16* __restrict__ xlo) {
    int i = blockIdx.x * blockDim.x + threadIdx.x;
    int stride = gridDim.x * blockDim.x;
    for (; i < NN * DIN; i += stride) {
        u16 hi, lo;
        split2(x[i], hi, lo);
        xhi[i] = hi;
        xlo[i] = lo;
    }
}

// ---------------- GEMM v5: g = (x @ W) * dinv[row], bf16 row-major out -------
// 512 threads = 8 waves as 4 row-panels x 2 col-panels over a 128 x Dc tile.
// Wave: 32 rows (2 rg of 16) x Dc/2 cols (NTW tiles of 16). Per K-slice per
// wave: 16 ds_read_b128 (192cyc) vs 48 MFMA (230cyc) -> MFMA-bound; per block
// per slice: 384 MFMA / 64KB staged (v2-level); VGPR ~105 with
// __launch_bounds__(512,4) -> 2 blocks/CU, 16 waves/CU latency hiding.
// C/D: col=lane&15, row=quad*4+reg.

template <int K, int Dc>
__global__ __launch_bounds__(512, 4) void gemm_kernel(const u16* __restrict__ xhi,
                                                      const u16* __restrict__ xlo,
                                                      const u16* __restrict__ whi,
                                                      const u16* __restrict__ wlo,
                                                      const float* __restrict__ dinv,
                                                      u16* __restrict__ g) {
    constexpr int NTW = Dc / 32;   // col-tiles per wave (8 for 256, 4 for 128)
    constexpr int KS = K / 32;
    __shared__ u16 bh[Dc * 32];
    __shared__ u16 bl[Dc * 32];
    const int tid = threadIdx.x;
    const int wid = tid >> 6;
    const int rowPanel = wid >> 1;       // 0..3
    const int colPanel = wid & 1;        // 0..1
    const int lane = tid & 63;
    const int m = lane & 15, quad = lane >> 4;
    const int rowBase = blockIdx.x * 128 + rowPanel * 32;

    f32x4 acc[2][NTW];
#pragma unroll
    for (int rg = 0; rg < 2; ++rg)
#pragma unroll
        for (int t = 0; t < NTW; ++t) acc[rg][t] = (f32x4){0.f, 0.f, 0.f, 0.f};

    size_t arow[2];
#pragma unroll
    for (int rg = 0; rg < 2; ++rg) {
        int rowA = rowBase + rg * 16 + m;
        if (rowA > NN - 1) rowA = NN - 1;
        arow[rg] = (size_t)rowA * K + quad * 8;
    }

    for (int ks = 0; ks < KS; ++ks) {
        const u16* sh_src = whi + (size_t)ks * Dc * 32;
        const u16* sl_src = wlo + (size_t)ks * Dc * 32;
        __syncthreads();  // protect LDS from previous iteration's readers
#pragma unroll
        for (int i = 0; i < Dc * 4; i += 512) {
            int j = i + tid;
            __builtin_amdgcn_global_load_lds((const AS1 void*)(sh_src + j * 8),
                                             (AS3 void*)((AS3 u16*)bh + j * 8), 16, 0, 0);
            __builtin_amdgcn_global_load_lds((const AS1 void*)(sl_src + j * 8),
                                             (AS3 void*)((AS3 u16*)bl + j * 8), 16, 0, 0);
        }
        short8 ah[2], al[2];
#pragma unroll
        for (int rg = 0; rg < 2; ++rg) {
            ah[rg] = *(const short8*)(xhi + arow[rg] + ks * 32);
            al[rg] = *(const short8*)(xlo + arow[rg] + ks * 32);
        }
        __syncthreads();  // staging complete
#pragma unroll
        for (int t = 0; t < NTW; ++t) {
            const int bo = ((colPanel * NTW + t) * 16 + m) * 32 + quad * 8;
            short8 wh = *(const short8*)(bh + bo);
            short8 wl = *(const short8*)(bl + bo);
#pragma unroll
            for (int rg = 0; rg < 2; ++rg) {
                acc[rg][t] = __builtin_amdgcn_mfma_f32_16x16x32_bf16(ah[rg], wh, acc[rg][t], 0, 0, 0);
                acc[rg][t] = __builtin_amdgcn_mfma_f32_16x16x32_bf16(al[rg], wh, acc[rg][t], 0, 0, 0);
                acc[rg][t] = __builtin_amdgcn_mfma_f32_16x16x32_bf16(ah[rg], wl, acc[rg][t], 0, 0, 0);
            }
        }
    }

#pragma unroll
    for (int rg = 0; rg < 2; ++rg) {
        const int r0 = rowBase + rg * 16 + quad * 4;
        float dv[4];
#pragma unroll
        for (int r = 0; r < 4; ++r) {
            int rr = r0 + r;
            dv[r] = (rr < NN) ? dinv[rr] : 0.f;
        }
#pragma unroll
        for (int t = 0; t < NTW; ++t) {
            const int col = colPanel * (Dc / 2) + t * 16 + m;
#pragma unroll
            for (int r = 0; r < 4; ++r) {
                int rr = r0 + r;
                if (rr < NN) g[(size_t)rr * Dc + col] = f2bf(acc[rg][t][r] * dv[r]);
            }
        }
    }
}

// ---------------- full-row aggregation + fused bias/LN/SiLU/split ------------
// wave per node; lane owns L = Dc/64 consecutive bf16 columns (full 512B row per
// edge = 8 contiguous lines -> at load-return BW ceiling). 8-deep unrolled.

template <int L>
__device__ __forceinline__ void loadg(const u16* p, float (&f)[L]);
template <>
__device__ __forceinline__ void loadg<4>(const u16* p, float (&f)[4]) {
    uint2 v = *(const uint2*)p;
    f[0] = bf2f(v.x & 0xffffu); f[1] = bf2f(v.x >> 16);
    f[2] = bf2f(v.y & 0xffffu); f[3] = bf2f(v.y >> 16);
}
template <>
__device__ __forceinline__ void loadg<2>(const u16* p, float (&f)[2]) {
    u32 v = *(const u32*)p;
    f[0] = bf2f(v & 0xffffu); f[1] = bf2f(v >> 16);
}

template <int Dc, bool FINAL>
__global__ __launch_bounds__(256) void agg_kernel(const u16* __restrict__ g,
                                                  const int* __restrict__ rowp,
                                                  const int* __restrict__ srcs,
                                                  const float* __restrict__ dinv,
                                                  const float* __restrict__ bias,
                                                  const float* __restrict__ gamma,
                                                  const float* __restrict__ beta,
                                                  float* __restrict__ outf,
                                                  u16* __restrict__ xhi,
                                                  u16* __restrict__ xlo) {
    constexpr int L = Dc / 64;
    const int wid = threadIdx.x >> 6, lane = threadIdx.x & 63;
    const int node = blockIdx.x * 4 + wid;
    const int coff = lane * L;

    float acc[L];
    loadg<L>(g + (size_t)node * Dc + coff, acc);  // self term

    int e = rowp[node];
    const int end = rowp[node + 1];
    for (; e + 8 <= end; e += 8) {
        int s0 = srcs[e],     s1 = srcs[e + 1], s2 = srcs[e + 2], s3 = srcs[e + 3];
        int s4 = srcs[e + 4], s5 = srcs[e + 5], s6 = srcs[e + 6], s7 = srcs[e + 7];
        float f0[L], f1[L], f2[L], f3[L], f4[L], f5[L], f6[L], f7[L];
        loadg<L>(g + (size_t)s0 * Dc + coff, f0);
        loadg<L>(g + (size_t)s1 * Dc + coff, f1);
        loadg<L>(g + (size_t)s2 * Dc + coff, f2);
        loadg<L>(g + (size_t)s3 * Dc + coff, f3);
        loadg<L>(g + (size_t)s4 * Dc + coff, f4);
        loadg<L>(g + (size_t)s5 * Dc + coff, f5);
        loadg<L>(g + (size_t)s6 * Dc + coff, f6);
        loadg<L>(g + (size_t)s7 * Dc + coff, f7);
#pragma unroll
        for (int j = 0; j < L; ++j)
            acc[j] += ((f0[j] + f1[j]) + (f2[j] + f3[j])) +
                      ((f4[j] + f5[j]) + (f6[j] + f7[j]));
    }
    for (; e < end; ++e) {
        float f[L];
        loadg<L>(g + (size_t)srcs[e] * Dc + coff, f);
#pragma unroll
        for (int j = 0; j < L; ++j) acc[j] += f[j];
    }

    const float dv = dinv[node];
    float v[L];
#pragma unroll
    for (int j = 0; j < L; ++j) v[j] = acc[j] * dv + bias[coff + j];

    if (FINAL) {
        if (L == 4) {
            f32x4 o = {v[0], v[1], v[2], v[3]};
            *(f32x4*)(outf + (size_t)node * Dc + coff) = o;
        } else {
            f32x2 o = {v[0], v[1]};
            *(f32x2*)(outf + (size_t)node * Dc + coff) = o;
        }
    } else {
        float s = 0.f, s2 = 0.f;
#pragma unroll
        for (int j = 0; j < L; ++j) {
            s += v[j];
            s2 += v[j] * v[j];
        }
        for (int off = 32; off > 0; off >>= 1) {
            s += __shfl_xor(s, off, 64);
            s2 += __shfl_xor(s2, off, 64);
        }
        const float mu = s * (1.f / Dc);
        const float var = s2 * (1.f / Dc) - mu * mu;
        const float rstd = rsqrtf(fmaxf(var, 0.f) + 1e-5f);
#pragma unroll
        for (int j = 0; j < L; ++j) {
            float y = (v[j] - mu) * rstd * gamma[coff + j] + beta[coff + j];
            v[j] = y / (1.f + __expf(-y));
        }
        u16 hh[L], ll[L];
#pragma unroll
        for (int j = 0; j < L; ++j) split2(v[j], hh[j], ll[j]);
        if (L == 4) {
            uint2 oh, ol;
            oh.x = (u32)hh[0] | ((u32)hh[1] << 16);
            oh.y = (u32)hh[2] | ((u32)hh[3] << 16);
            ol.x = (u32)ll[0] | ((u32)ll[1] << 16);
            ol.y = (u32)ll[2] | ((u32)ll[3] << 16);
            *(uint2*)(xhi + (size_t)node * Dc + coff) = oh;
            *(uint2*)(xlo + (size_t)node * Dc + coff) = ol;
        } else {
            *(u32*)(xhi + (size_t)node * Dc + coff) = (u32)hh[0] | ((u32)hh[1] << 16);
            *(u32*)(xlo + (size_t)node * Dc + coff) = (u32)ll[0] | ((u32)ll[1] << 16);
        }
    }
}

// ---------------- launcher ----------------

extern "C" void kernel_launch(void* const* d_in, const int* in_sizes, int n_in,
                              void* d_out, int out_size, void* d_ws, size_t ws_size,
                              hipStream_t stream) {
    (void)in_sizes; (void)n_in; (void)out_size; (void)ws_size;
    const float* x_in  = (const float*)d_in[0];
    const int*   ei    = (const int*)d_in[1];
    const float* W_in  = (const float*)d_in[2];
    const float* b_in  = (const float*)d_in[3];
    const float* W_mid = (const float*)d_in[4];
    const float* b_mid = (const float*)d_in[5];
    const float* W_out = (const float*)d_in[6];
    const float* b_out = (const float*)d_in[7];
    const float* gamma = (const float*)d_in[8];
    const float* beta  = (const float*)d_in[9];

    char* ws = (char*)d_ws;
    size_t off = 0;
    auto alloc = [&](size_t bytes) -> char* {
        char* p = ws + off;
        off += (bytes + 255) & ~(size_t)255;
        return p;
    };
    float* dinv   = (float*)alloc((size_t)NN * 4);
    int* counts   = (int*)alloc((size_t)NN * 4);
    int* rowp     = (int*)alloc((size_t)(NN + 1) * 4);
    int* rank     = (int*)alloc((size_t)NE * 4);
    int* srcs     = (int*)alloc((size_t)NE * 4);
    u16* whi_in   = (u16*)alloc((size_t)DIN * DMID * 2);
    u16* wlo_in   = (u16*)alloc((size_t)DIN * DMID * 2);
    u16* whi_mid  = (u16*)alloc((size_t)NMID * DMID * DMID * 2);
    u16* wlo_mid  = (u16*)alloc((size_t)NMID * DMID * DMID * 2);
    u16* whi_out  = (u16*)alloc((size_t)DMID * DOUT * 2);
    u16* wlo_out  = (u16*)alloc((size_t)DMID * DOUT * 2);
    u16* xhi      = (u16*)alloc((size_t)NN * DMID * 2);
    u16* xlo      = (u16*)alloc((size_t)NN * DMID * 2);
    u16* g        = (u16*)alloc((size_t)NN * DMID * 2);

    hipMemsetAsync(counts, 0, (size_t)NN * 4, stream);
    const int EB4 = (NE / 4 + 255) / 256;  // 1563: one int4 group per thread
    rank_kernel<<<EB4, 256, 0, stream>>>(ei, counts, rank);
    dinv_kernel<<<(NN + 255) / 256, 256, 0, stream>>>(counts, dinv);
    scan_kernel<<<1, 1024, 0, stream>>>(counts, rowp);
    scatter_kernel<<<EB4, 256, 0, stream>>>(ei, rowp, rank, srcs);

    wsplit_kernel<<<(DIN * DMID + 255) / 256, 256, 0, stream>>>(W_in, whi_in, wlo_in, DIN, DMID);
    for (int i = 0; i < NMID; ++i)
        wsplit_kernel<<<(DMID * DMID + 255) / 256, 256, 0, stream>>>(
            W_mid + (size_t)i * DMID * DMID, whi_mid + (size_t)i * DMID * DMID,
            wlo_mid + (size_t)i * DMID * DMID, DMID, DMID);
    wsplit_kernel<<<(DMID * DOUT + 255) / 256, 256, 0, stream>>>(W_out, whi_out, wlo_out, DMID, DOUT);
    xsplit_kernel<<<1024, 256, 0, stream>>>(x_in, xhi, xlo);

    const int GB = (NN + 127) / 128;  // 391 (8 waves/block, 128 x Dc tile)
    const int NB = NN / 4;            // 12500 (4 waves/block, wave per node)

    // layer 0: 128 -> 256
    gemm_kernel<DIN, DMID><<<GB, 512, 0, stream>>>(xhi, xlo, whi_in, wlo_in, dinv, g);
    agg_kernel<DMID, false><<<NB, 256, 0, stream>>>(g, rowp, srcs, dinv, b_in,
                                                    gamma, beta, nullptr, xhi, xlo);
    // 8 mid layers: 256 -> 256
    for (int i = 0; i < NMID; ++i) {
        gemm_kernel<DMID, DMID><<<GB, 512, 0, stream>>>(xhi, xlo,
                                                        whi_mid + (size_t)i * DMID * DMID,
                                                        wlo_mid + (size_t)i * DMID * DMID,
                                                        dinv, g);
        agg_kernel<DMID, false><<<NB, 256, 0, stream>>>(g, rowp, srcs, dinv,
                                                        b_mid + (size_t)i * DMID,
                                                        gamma + (size_t)(i + 1) * DMID,
                                                        beta + (size_t)(i + 1) * DMID,
                                                        nullptr, xhi, xlo);
    }
    // final layer: 256 -> 128, no LN/SiLU
    gemm_kernel<DMID, DOUT><<<GB, 512, 0, stream>>>(xhi, xlo, whi_out, wlo_out, dinv, g);
    agg_kernel<DOUT, true><<<NB, 256, 0, stream>>>(g, rowp, srcs, dinv, b_out,
                                                   nullptr, nullptr, (float*)d_out,
                                                   nullptr, nullptr);
}